// Round 5
// baseline (389.124 us; speedup 1.0000x reference)
//
#include <hip/hip_runtime.h>

static __device__ __forceinline__ float relu_f(float v) { return fmaxf(v, 0.f); }

// fp32 -> bf16 round-to-nearest-even
static __device__ __forceinline__ unsigned short f2bf(float f) {
  unsigned u = __float_as_uint(f);
  u += 0x7fffu + ((u >> 16) & 1u);
  return (unsigned short)(u >> 16);
}
static __device__ __forceinline__ float bf2f(unsigned short h) {
  return __uint_as_float(((unsigned)h) << 16);
}

// Fused K1: blocks [0,nbn): per 64-node tile xw(bf16)=x@MK, out[:,64:]=relu(x@SK+b).
//           blocks [nbn,grid): grid-stride in-degree count (int atomics, nt reads).
__global__ __launch_bounds__(256) void k_gemm_count(
    const float* __restrict__ x, const float* __restrict__ mk,
    const float* __restrict__ sk, const float* __restrict__ bias,
    unsigned short* __restrict__ xwh, float* __restrict__ out, int n_nodes,
    const int* __restrict__ row, int* __restrict__ cnt, int n_edges, int nbn)
{
  __shared__ float s_mk[64][64];
  __shared__ float s_sk[64][64];
  __shared__ float s_xT[64][68];
  const int tid = threadIdx.x;

  if ((int)blockIdx.x >= nbn) {                 // ---- count role ----
    const int vb = blockIdx.x - nbn;
    const int nvb = gridDim.x - nbn;
    for (int e = vb * 256 + tid; e < n_edges; e += nvb * 256) {
      int r = __builtin_nontemporal_load(&row[e]);
      atomicAdd(&cnt[r], 1);
    }
    return;
  }
  // ---- gemm role ----
  for (int i = tid; i < 4096; i += 256) {
    s_mk[i >> 6][i & 63] = mk[i];
    s_sk[i >> 6][i & 63] = sk[i];
  }
  const int node0 = blockIdx.x * 64;
  for (int i = tid; i < 4096; i += 256) {
    int nl = i >> 6, f = i & 63;
    int n = node0 + nl;
    s_xT[f][nl] = (n < n_nodes) ? x[(size_t)n * 64 + f] : 0.f;
  }
  __syncthreads();
  const int g  = tid >> 4;
  const int ub = (tid & 15) * 4;
  float am[4][4] = {{0.f}};
  float as[4][4] = {{0.f}};
  for (int f = 0; f < 64; ++f) {
    float4 wm = *(const float4*)&s_mk[f][ub];
    float4 ws = *(const float4*)&s_sk[f][ub];
    float4 xv = *(const float4*)&s_xT[f][4 * g];
    const float xs[4] = {xv.x, xv.y, xv.z, xv.w};
#pragma unroll
    for (int j = 0; j < 4; ++j) {
      am[j][0] += xs[j] * wm.x; am[j][1] += xs[j] * wm.y;
      am[j][2] += xs[j] * wm.z; am[j][3] += xs[j] * wm.w;
      as[j][0] += xs[j] * ws.x; as[j][1] += xs[j] * ws.y;
      as[j][2] += xs[j] * ws.z; as[j][3] += xs[j] * ws.w;
    }
  }
  float4 bv = *(const float4*)&bias[64 + ub];
#pragma unroll
  for (int j = 0; j < 4; ++j) {
    int n = node0 + 4 * g + j;
    if (n >= n_nodes) break;
    *(ushort4*)&xwh[(size_t)n * 64 + ub] =
        make_ushort4(f2bf(am[j][0]), f2bf(am[j][1]), f2bf(am[j][2]), f2bf(am[j][3]));
    *(float4*)&out[(size_t)n * 128 + 64 + ub] =
        make_float4(relu_f(as[j][0] + bv.x), relu_f(as[j][1] + bv.y),
                    relu_f(as[j][2] + bv.z), relu_f(as[j][3] + bv.w));
  }
}

// Single-kernel exclusive scan: block computes its own prefix by striding cnt[0..base).
__global__ __launch_bounds__(1024) void k_scan(
    const int* __restrict__ cnt, int* __restrict__ off, int n)
{
  __shared__ int s[1024];
  __shared__ int sp[256];
  const int tid = threadIdx.x;
  const int base = blockIdx.x * 1024;
  if (tid < 256) {
    int acc = 0;
    for (int j = tid; j < base; j += 256) acc += cnt[j];
    sp[tid] = acc;
  }
  const int i = base + tid;
  const int v = (i < n) ? cnt[i] : 0;
  s[tid] = v;
  __syncthreads();
  for (int d = 128; d > 0; d >>= 1) {
    if (tid < d) sp[tid] += sp[tid + d];
    __syncthreads();
  }
  for (int d = 1; d < 1024; d <<= 1) {
    int t = (tid >= d) ? s[tid - d] : 0;
    __syncthreads();
    s[tid] += t;
    __syncthreads();
  }
  if (i < n) off[i] = s[tid] - v + sp[0];
}

// XCD-sliced CSR build; streaming inputs marked non-temporal (evict-first) so the
// dirty elist window (~1.6 MB/XCD) survives in L2 long enough to merge full lines.
__global__ __launch_bounds__(256) void k_build_sliced(
    const int* __restrict__ row, const int* __restrict__ col,
    const float* __restrict__ ew, int* __restrict__ off,
    int2* __restrict__ elist, int n_edges, int n_nodes)
{
  const int slice = blockIdx.x & 7;
  const int vb    = blockIdx.x >> 3;
  const int nvb   = gridDim.x >> 3;
  const int sliceN = (n_nodes + 7) >> 3;
  const int lo = slice * sliceN;
  const int hi = min(lo + sliceN, n_nodes);
  for (int e = vb * 256 + threadIdx.x; e < n_edges; e += nvb * 256) {
    int r = __builtin_nontemporal_load(&row[e]);
    if (r >= lo && r < hi) {
      int pos = atomicAdd(&off[r], 1);
      int c   = __builtin_nontemporal_load(&col[e]);
      float w = __builtin_nontemporal_load(&ew[e]);
      elist[pos] = make_int2(c, __float_as_int(w));
    }
  }
}

// Fused: per-node mean of relu(w*xw[col]+mb), then @nk + bias + relu.
// elist streamed non-temporally so the 12.8 MB bf16 xw table stays L2-resident.
__global__ __launch_bounds__(256) void k_fused_reduce_gemm(
    const int* __restrict__ cnt, const int* __restrict__ off,
    const int2* __restrict__ elist, const unsigned short* __restrict__ xwh,
    const float* __restrict__ mb, const float* __restrict__ nk,
    const float* __restrict__ bias, float* __restrict__ out, int n_nodes)
{
  __shared__ float s_nk[64][64];
  __shared__ float s_rh[16][68];
  const int tid = threadIdx.x;
  for (int i = tid; i < 1024; i += 256) {
    *(float4*)&s_nk[0][4 * i] = *(const float4*)&nk[4 * i];
  }
  const int node_l = tid >> 4;
  const int q = tid & 15;
  const int n = blockIdx.x * 16 + node_l;
  float4 acc = make_float4(0.f, 0.f, 0.f, 0.f);
  if (n < n_nodes) {
    const float4 mbq = *(const float4*)&mb[4 * q];
    const int c = cnt[n];
    const int end = off[n];        // after build, off[n] == end
    int i = end - c;
    for (; i + 2 <= end; i += 2) {
      unsigned long long p0 =
          __builtin_nontemporal_load((const unsigned long long*)&elist[i]);
      unsigned long long p1 =
          __builtin_nontemporal_load((const unsigned long long*)&elist[i + 1]);
      int c0 = (int)(p0 & 0xffffffffu), c1 = (int)(p1 & 0xffffffffu);
      float w0 = __uint_as_float((unsigned)(p0 >> 32));
      float w1 = __uint_as_float((unsigned)(p1 >> 32));
      ushort4 u0 = *(const ushort4*)&xwh[(size_t)c0 * 64 + 4 * q];
      ushort4 u1 = *(const ushort4*)&xwh[(size_t)c1 * 64 + 4 * q];
      acc.x += relu_f(w0 * bf2f(u0.x) + mbq.x);
      acc.y += relu_f(w0 * bf2f(u0.y) + mbq.y);
      acc.z += relu_f(w0 * bf2f(u0.z) + mbq.z);
      acc.w += relu_f(w0 * bf2f(u0.w) + mbq.w);
      acc.x += relu_f(w1 * bf2f(u1.x) + mbq.x);
      acc.y += relu_f(w1 * bf2f(u1.y) + mbq.y);
      acc.z += relu_f(w1 * bf2f(u1.z) + mbq.z);
      acc.w += relu_f(w1 * bf2f(u1.w) + mbq.w);
    }
    if (i < end) {
      unsigned long long p0 =
          __builtin_nontemporal_load((const unsigned long long*)&elist[i]);
      int c0 = (int)(p0 & 0xffffffffu);
      float w0 = __uint_as_float((unsigned)(p0 >> 32));
      ushort4 u0 = *(const ushort4*)&xwh[(size_t)c0 * 64 + 4 * q];
      acc.x += relu_f(w0 * bf2f(u0.x) + mbq.x);
      acc.y += relu_f(w0 * bf2f(u0.y) + mbq.y);
      acc.z += relu_f(w0 * bf2f(u0.z) + mbq.z);
      acc.w += relu_f(w0 * bf2f(u0.w) + mbq.w);
    }
    const float inv = 1.0f / fmaxf((float)c, 1.0f);
    acc.x *= inv; acc.y *= inv; acc.z *= inv; acc.w *= inv;
  }
  *(float4*)&s_rh[node_l][4 * q] = acc;
  __syncthreads();
  float4 o = make_float4(0.f, 0.f, 0.f, 0.f);
  for (int f = 0; f < 64; ++f) {
    float rv = s_rh[node_l][f];
    float4 wv = *(const float4*)&s_nk[f][4 * q];
    o.x += rv * wv.x; o.y += rv * wv.y; o.z += rv * wv.z; o.w += rv * wv.w;
  }
  if (n < n_nodes) {
    float4 bv = *(const float4*)&bias[4 * q];
    *(float4*)&out[(size_t)n * 128 + 4 * q] =
        make_float4(relu_f(o.x + bv.x), relu_f(o.y + bv.y),
                    relu_f(o.z + bv.z), relu_f(o.w + bv.w));
  }
}

extern "C" void kernel_launch(void* const* d_in, const int* in_sizes, int n_in,
                              void* d_out, int out_size, void* d_ws, size_t ws_size,
                              hipStream_t stream) {
  const float* x    = (const float*)d_in[0];
  const int*   ei   = (const int*)d_in[1];     // [2, E]
  const float* ew   = (const float*)d_in[2];
  const float* mk   = (const float*)d_in[3];
  const float* mb   = (const float*)d_in[4];
  const float* nk   = (const float*)d_in[5];
  const float* sk   = (const float*)d_in[6];
  const float* bias = (const float*)d_in[7];
  float* out = (float*)d_out;

  const int n_nodes = in_sizes[0] / 64;
  const int n_edges = in_sizes[2];
  const int* row = ei;
  const int* col = ei + n_edges;

  // ws layout
  unsigned short* xwh = (unsigned short*)d_ws;              // [N*64] bf16
  int*  cnt  = (int*)(xwh + (size_t)n_nodes * 64);          // [N]
  int*  off  = cnt + n_nodes;                               // [N]
  size_t ebytes = ((size_t)(off + n_nodes) - (size_t)d_ws + 7) & ~(size_t)7;
  int2* elist = (int2*)((char*)d_ws + ebytes);              // [E]

  hipMemsetAsync(cnt, 0, (size_t)n_nodes * sizeof(int), stream);

  const int nbn = (n_nodes + 63) / 64;
  k_gemm_count<<<nbn + 512, 256, 0, stream>>>(x, mk, sk, bias, xwh, out, n_nodes,
                                              row, cnt, n_edges, nbn);

  const int nb_scan = (n_nodes + 1023) / 1024;
  k_scan<<<nb_scan, 1024, 0, stream>>>(cnt, off, n_nodes);

  k_build_sliced<<<2048, 256, 0, stream>>>(row, col, ew, off, elist, n_edges, n_nodes);

  const int nbf = (n_nodes + 15) / 16;
  k_fused_reduce_gemm<<<nbf, 256, 0, stream>>>(cnt, off, elist, xwh, mb, nk, bias,
                                               out, n_nodes);
}